// Round 1
// baseline (1002.274 us; speedup 1.0000x reference)
//
#include <hip/hip_runtime.h>
#include <math.h>

#define NN 50000
#define EE 800000
#define EP (EE + NN)
#define GG 512
#define OUTC 100
#define NEG 0.2f

// ---------------- CSR build ----------------
__global__ __launch_bounds__(256) void k_hist(const int* __restrict__ ei, int* __restrict__ deg) {
  int e = blockIdx.x * 256 + threadIdx.x;
  if (e >= EP) return;
  int d = (e < EE) ? ei[EE + e] : (e - EE);
  atomicAdd(&deg[d], 1);
}

__global__ __launch_bounds__(1024) void k_scan(const int* __restrict__ deg, int* __restrict__ offs) {
  __shared__ int tmp[1024];
  int tid = threadIdx.x;
  int carry = 0;
  for (int base = 0; base < NN; base += 1024) {
    int i = base + tid;
    int v = (i < NN) ? deg[i] : 0;
    tmp[tid] = v;
    __syncthreads();
    for (int off = 1; off < 1024; off <<= 1) {
      int t = (tid >= off) ? tmp[tid - off] : 0;
      __syncthreads();
      tmp[tid] += t;
      __syncthreads();
    }
    if (i < NN) offs[i + 1] = carry + tmp[tid];
    int tot = tmp[1023];
    __syncthreads();
    carry += tot;
  }
  if (tid == 0) offs[0] = 0;
}

__global__ __launch_bounds__(256) void k_scatter(const int* __restrict__ ei,
    const int* __restrict__ offs, int* __restrict__ cursor,
    int* __restrict__ srcs, int* __restrict__ eids) {
  int e = blockIdx.x * 256 + threadIdx.x;
  if (e >= EP) return;
  int s, d;
  if (e < EE) { s = ei[e]; d = ei[EE + e]; } else { s = e - EE; d = s; }
  int pos = offs[d] + atomicAdd(&cursor[d], 1);
  srcs[pos] = s;
  eids[pos] = e;
}

// ---------------- GEMM: h = feat @ W^T  (W is [128 out][128 in] row-major) ----------------
__global__ __launch_bounds__(256) void k_gemm(const float* __restrict__ feat,
                                              const float* __restrict__ W,
                                              float* __restrict__ h) {
  __shared__ float sf[128 * 128];  // 64 KB, rotation-swizzled rows
  int n0 = blockIdx.x * 128;
  for (int idx = threadIdx.x * 4; idx < 128 * 128; idx += 256 * 4) {
    int r = idx >> 7, k = idx & 127;
    float4 v = make_float4(0.f, 0.f, 0.f, 0.f);
    int n = n0 + r;
    if (n < NN) v = *(const float4*)&feat[n * 128 + k];
    int kk = (k + ((r >> 2) << 2)) & 127;   // rotate by 4*(r/4) words -> conflict-free reads
    *(float4*)&sf[r * 128 + kk] = v;
  }
  __syncthreads();
  int cg = threadIdx.x & 7;      // 8 channel-groups of 16
  int ng = threadIdx.x >> 3;     // 32 node-groups of 4
  float acc[4][16];
#pragma unroll
  for (int i = 0; i < 4; i++)
#pragma unroll
    for (int c = 0; c < 16; c++) acc[i][c] = 0.f;
  for (int k0 = 0; k0 < 128; k0 += 4) {
    float4 fa[4];
#pragma unroll
    for (int i = 0; i < 4; i++) {
      int r = ng * 4 + i;
      int kk = (k0 + ((r >> 2) << 2)) & 127;
      fa[i] = *(const float4*)&sf[r * 128 + kk];
    }
#pragma unroll
    for (int c = 0; c < 16; c++) {
      float4 w = *(const float4*)&W[(cg * 16 + c) * 128 + k0];
#pragma unroll
      for (int i = 0; i < 4; i++)
        acc[i][c] = fmaf(fa[i].x, w.x, fmaf(fa[i].y, w.y, fmaf(fa[i].z, w.z, fmaf(fa[i].w, w.w, acc[i][c]))));
    }
  }
#pragma unroll
  for (int i = 0; i < 4; i++) {
    int n = n0 + ng * 4 + i;
    if (n < NN) {
#pragma unroll
      for (int c = 0; c < 16; c += 4) {
        float4 o = make_float4(acc[i][c], acc[i][c + 1], acc[i][c + 2], acc[i][c + 3]);
        *(float4*)&h[n * 128 + cg * 16 + c] = o;
      }
    }
  }
}

// ---------------- per-node attention logits ----------------
__global__ __launch_bounds__(256) void k_att(const float* __restrict__ h,
    const float* __restrict__ att_s, const float* __restrict__ att_d,
    float* __restrict__ asrc, float* __restrict__ adst) {
  int t = blockIdx.x * 256 + threadIdx.x;
  if (t >= NN * 4) return;
  int n = t >> 2, hd = t & 3;
  const float4* hp = (const float4*)&h[n * 128 + hd * 32];
  const float4* sp = (const float4*)&att_s[hd * 32];
  const float4* dp = (const float4*)&att_d[hd * 32];
  float sa = 0.f, sd = 0.f;
#pragma unroll
  for (int i = 0; i < 8; i++) {
    float4 hv = hp[i], sv = sp[i], dv = dp[i];
    sa += hv.x * sv.x + hv.y * sv.y + hv.z * sv.z + hv.w * sv.w;
    sd += hv.x * dv.x + hv.y * dv.y + hv.z * dv.z + hv.w * dv.w;
  }
  asrc[t] = sa;
  adst[t] = sd;
}

// ---------------- per-edge raw attention (leaky-relu) ----------------
__global__ __launch_bounds__(256) void k_alpha(const int* __restrict__ ei,
    const float4* __restrict__ asrc, const float4* __restrict__ adst,
    float4* __restrict__ alpha) {
  int e = blockIdx.x * 256 + threadIdx.x;
  if (e >= EP) return;
  int s, d;
  if (e < EE) { s = ei[e]; d = ei[EE + e]; } else { s = e - EE; d = s; }
  float4 a = asrc[s], bd = adst[d];
  float4 r; float v;
  v = a.x + bd.x; r.x = v > 0.f ? v : NEG * v;
  v = a.y + bd.y; r.y = v > 0.f ? v : NEG * v;
  v = a.z + bd.z; r.z = v > 0.f ? v : NEG * v;
  v = a.w + bd.w; r.w = v > 0.f ? v : NEG * v;
  alpha[e] = r;
}

// ---------------- per-dst segment softmax + weighted aggregation + bias + ELU ----------------
__global__ __launch_bounds__(64) void k_agg(const float* __restrict__ h,
    const float4* __restrict__ alpha, const int* __restrict__ offs,
    const int* __restrict__ srcs, const int* __restrict__ eids,
    const float* __restrict__ bias, float* __restrict__ outf) {
  int node = blockIdx.x;
  int lane = threadIdx.x;
  int e0 = offs[node], e1 = offs[node + 1];

  // online softmax stats, 4 heads, per lane
  float m0 = -1e30f, m1 = -1e30f, m2 = -1e30f, m3 = -1e30f;
  float s0 = 0.f, s1 = 0.f, s2 = 0.f, s3 = 0.f;
  for (int j = e0 + lane; j < e1; j += 64) {
    float4 a = alpha[eids[j]];
    float nm;
    nm = fmaxf(m0, a.x); s0 = s0 * expf(m0 - nm) + expf(a.x - nm); m0 = nm;
    nm = fmaxf(m1, a.y); s1 = s1 * expf(m1 - nm) + expf(a.y - nm); m1 = nm;
    nm = fmaxf(m2, a.z); s2 = s2 * expf(m2 - nm) + expf(a.z - nm); m2 = nm;
    nm = fmaxf(m3, a.w); s3 = s3 * expf(m3 - nm) + expf(a.w - nm); m3 = nm;
  }
#pragma unroll
  for (int off = 32; off > 0; off >>= 1) {
    float om, os, nm;
    om = __shfl_xor(m0, off); os = __shfl_xor(s0, off);
    nm = fmaxf(m0, om); s0 = s0 * expf(m0 - nm) + os * expf(om - nm); m0 = nm;
    om = __shfl_xor(m1, off); os = __shfl_xor(s1, off);
    nm = fmaxf(m1, om); s1 = s1 * expf(m1 - nm) + os * expf(om - nm); m1 = nm;
    om = __shfl_xor(m2, off); os = __shfl_xor(s2, off);
    nm = fmaxf(m2, om); s2 = s2 * expf(m2 - nm) + os * expf(om - nm); m2 = nm;
    om = __shfl_xor(m3, off); os = __shfl_xor(s3, off);
    nm = fmaxf(m3, om); s3 = s3 * expf(m3 - nm) + os * expf(om - nm); m3 = nm;
  }
  float r0 = 1.0f / (s0 + 1e-16f);
  float r1 = 1.0f / (s1 + 1e-16f);
  float r2 = 1.0f / (s2 + 1e-16f);
  float r3 = 1.0f / (s3 + 1e-16f);

  int head = lane >> 4;           // channels 2*lane, 2*lane+1 -> head = lane/16
  __shared__ int s_src[64];
  __shared__ float s_w[64 * 4];
  float accx = 0.f, accy = 0.f;
  for (int base = e0; base < e1; base += 64) {
    __syncthreads();
    int j = base + lane;
    if (j < e1) {
      s_src[lane] = srcs[j];
      float4 a = alpha[eids[j]];
      s_w[lane * 4 + 0] = expf(a.x - m0) * r0;
      s_w[lane * 4 + 1] = expf(a.y - m1) * r1;
      s_w[lane * 4 + 2] = expf(a.z - m2) * r2;
      s_w[lane * 4 + 3] = expf(a.w - m3) * r3;
    }
    __syncthreads();
    int cnt = min(64, e1 - base);
    for (int k = 0; k < cnt; k++) {
      int sn = s_src[k];
      float w = s_w[(k << 2) + head];
      float2 hv = *(const float2*)&h[sn * 128 + (lane << 1)];
      accx = fmaf(w, hv.x, accx);
      accy = fmaf(w, hv.y, accy);
    }
  }
  int c0 = lane << 1;
  float o0 = accx + bias[c0];
  float o1 = accy + bias[c0 + 1];
  o0 = o0 > 0.f ? o0 : expm1f(o0);
  o1 = o1 > 0.f ? o1 : expm1f(o1);
  float2 o = make_float2(o0, o1);
  *(float2*)&outf[node * 128 + c0] = o;
}

// ---------------- mean pool (batch sorted -> run-length compressed atomics) ----------------
__global__ __launch_bounds__(128) void k_pool(const float* __restrict__ feat,
    const int* __restrict__ batch, float* __restrict__ pooled, float* __restrict__ cnt) {
  int n0 = blockIdx.x * 32;
  int c = threadIdx.x;
  float acc = 0.f; int curg = -1;
  for (int i = 0; i < 32; i++) {
    int n = n0 + i;
    if (n >= NN) break;
    int g = batch[n];
    if (g != curg) {
      if (curg >= 0) atomicAdd(&pooled[curg * 128 + c], acc);
      acc = 0.f; curg = g;
    }
    acc += feat[n * 128 + c];
  }
  if (curg >= 0) atomicAdd(&pooled[curg * 128 + c], acc);
  if (threadIdx.x == 0) {
    float cc = 0.f; int cg = -1;
    for (int i = 0; i < 32; i++) {
      int n = n0 + i;
      if (n >= NN) break;
      int g = batch[n];
      if (g != cg) { if (cg >= 0) atomicAdd(&cnt[cg], cc); cc = 0.f; cg = g; }
      cc += 1.f;
    }
    if (cg >= 0) atomicAdd(&cnt[cg], cc);
  }
}

// ---------------- final FC ----------------
__global__ __launch_bounds__(128) void k_fc(const float* __restrict__ pooled,
    const float* __restrict__ cnt, const float* __restrict__ fcW,
    const float* __restrict__ fcb, float* __restrict__ out) {
  int g = blockIdx.x;
  __shared__ float p[128];
  int t = threadIdx.x;
  float inv = 1.0f / fmaxf(cnt[g], 1.0f);
  p[t] = pooled[g * 128 + t] * inv;
  __syncthreads();
  if (t < OUTC) {
    float acc = fcb[t];
    const float4* wr = (const float4*)&fcW[t * 128];
    const float4* pp = (const float4*)p;
#pragma unroll
    for (int i = 0; i < 32; i++) {
      float4 w = wr[i], pv = pp[i];
      acc = fmaf(w.x, pv.x, fmaf(w.y, pv.y, fmaf(w.z, pv.z, fmaf(w.w, pv.w, acc))));
    }
    out[g * OUTC + t] = acc;
  }
}

extern "C" void kernel_launch(void* const* d_in, const int* in_sizes, int n_in,
                              void* d_out, int out_size, void* d_ws, size_t ws_size,
                              hipStream_t stream) {
  const float* x    = (const float*)d_in[0];
  const int*   ei   = (const int*)d_in[1];
  const int*   batch= (const int*)d_in[2];
  const float* W1   = (const float*)d_in[3];
  const float* as1  = (const float*)d_in[4];
  const float* ad1  = (const float*)d_in[5];
  const float* b1   = (const float*)d_in[6];
  const float* W2   = (const float*)d_in[7];
  const float* as2  = (const float*)d_in[8];
  const float* ad2  = (const float*)d_in[9];
  const float* b2   = (const float*)d_in[10];
  const float* W3   = (const float*)d_in[11];
  const float* as3  = (const float*)d_in[12];
  const float* ad3  = (const float*)d_in[13];
  const float* b3   = (const float*)d_in[14];
  const float* fcW  = (const float*)d_in[15];
  const float* fcb  = (const float*)d_in[16];
  float* out = (float*)d_out;

  char* p = (char*)d_ws;
  auto alloc = [&](size_t bytes) { char* r = p; p += (bytes + 255) & ~(size_t)255; return r; };
  float* h      = (float*)alloc((size_t)NN * 128 * 4);
  float* buf0   = (float*)alloc((size_t)NN * 128 * 4);
  float* asrc   = (float*)alloc((size_t)NN * 4 * 4);
  float* adst   = (float*)alloc((size_t)NN * 4 * 4);
  float* alpha  = (float*)alloc((size_t)EP * 4 * 4);
  int*   deg    = (int*)alloc((size_t)NN * 4);
  int*   offs   = (int*)alloc((size_t)(NN + 1) * 4);
  int*   cursor = (int*)alloc((size_t)NN * 4);
  int*   srcs   = (int*)alloc((size_t)EP * 4);
  int*   eids   = (int*)alloc((size_t)EP * 4);
  float* pooled = (float*)alloc((size_t)GG * 128 * 4);
  float* cnt    = (float*)alloc((size_t)GG * 4);

  hipMemsetAsync(deg, 0, (size_t)NN * 4, stream);
  hipMemsetAsync(cursor, 0, (size_t)NN * 4, stream);
  hipMemsetAsync(pooled, 0, (size_t)GG * 128 * 4, stream);
  hipMemsetAsync(cnt, 0, (size_t)GG * 4, stream);

  k_hist<<<(EP + 255) / 256, 256, 0, stream>>>(ei, deg);
  k_scan<<<1, 1024, 0, stream>>>(deg, offs);
  k_scatter<<<(EP + 255) / 256, 256, 0, stream>>>(ei, offs, cursor, srcs, eids);

  const float* Ws[3]  = {W1, W2, W3};
  const float* ass[3] = {as1, as2, as3};
  const float* ads[3] = {ad1, ad2, ad3};
  const float* bs[3]  = {b1, b2, b3};
  const float* fin = x;
  for (int l = 0; l < 3; l++) {
    k_gemm<<<(NN + 127) / 128, 256, 0, stream>>>(fin, Ws[l], h);
    k_att<<<(NN * 4 + 255) / 256, 256, 0, stream>>>(h, ass[l], ads[l], asrc, adst);
    k_alpha<<<(EP + 255) / 256, 256, 0, stream>>>(ei, (const float4*)asrc, (const float4*)adst, (float4*)alpha);
    k_agg<<<NN, 64, 0, stream>>>(h, (const float4*)alpha, offs, srcs, eids, bs[l], buf0);
    fin = buf0;
  }
  k_pool<<<(NN + 31) / 32, 128, 0, stream>>>(buf0, batch, pooled, cnt);
  k_fc<<<GG, 128, 0, stream>>>(pooled, cnt, fcW, fcb, out);
}

// Round 2
// 717.918 us; speedup vs baseline: 1.3961x; 1.3961x over previous
//
#include <hip/hip_runtime.h>
#include <math.h>

#define NN 50000
#define EE 800000
#define EP (EE + NN)
#define GG 512
#define OUTC 100
#define NEG 0.2f

typedef __attribute__((ext_vector_type(8))) short bf16x8;
typedef __attribute__((ext_vector_type(8))) unsigned short us8;
typedef __attribute__((ext_vector_type(4))) float f32x4;

__device__ inline ushort f2bf(float v) {
  unsigned u = __float_as_uint(v);
  unsigned r = (u + 0x7fff + ((u >> 16) & 1)) >> 16;
  return (ushort)r;
}

// ---------------- CSR build ----------------
__global__ __launch_bounds__(256) void k_hist(const int* __restrict__ ei, int* __restrict__ deg) {
  int e = blockIdx.x * 256 + threadIdx.x;
  if (e >= EP) return;
  int d = (e < EE) ? ei[EE + e] : (e - EE);
  atomicAdd(&deg[d], 1);
}

__global__ __launch_bounds__(1024) void k_scan(const int* __restrict__ deg, int* __restrict__ offs) {
  __shared__ int tmp[1024];
  int tid = threadIdx.x;
  int carry = 0;
  for (int base = 0; base < NN; base += 1024) {
    int i = base + tid;
    int v = (i < NN) ? deg[i] : 0;
    tmp[tid] = v;
    __syncthreads();
    for (int off = 1; off < 1024; off <<= 1) {
      int t = (tid >= off) ? tmp[tid - off] : 0;
      __syncthreads();
      tmp[tid] += t;
      __syncthreads();
    }
    if (i < NN) offs[i + 1] = carry + tmp[tid];
    int tot = tmp[1023];
    __syncthreads();
    carry += tot;
  }
  if (tid == 0) offs[0] = 0;
}

__global__ __launch_bounds__(256) void k_scatter(const int* __restrict__ ei,
    const int* __restrict__ offs, int* __restrict__ cursor,
    int* __restrict__ srcs, int* __restrict__ eids) {
  int e = blockIdx.x * 256 + threadIdx.x;
  if (e >= EP) return;
  int s, d;
  if (e < EE) { s = ei[e]; d = ei[EE + e]; } else { s = e - EE; d = s; }
  int pos = offs[d] + atomicAdd(&cursor[d], 1);
  srcs[pos] = s;
  eids[pos] = e;
}

// ---------------- split W (fp32 -> bf16 hi/lo), 128x128 ----------------
__global__ __launch_bounds__(256) void k_split(const float* __restrict__ W,
    ushort* __restrict__ hi, ushort* __restrict__ lo) {
  int i = blockIdx.x * 256 + threadIdx.x;
  if (i >= 128 * 128) return;
  float v = W[i];
  ushort hb = f2bf(v);
  float hf = __uint_as_float(((unsigned)hb) << 16);
  hi[i] = hb;
  lo[i] = f2bf(v - hf);
}

// ---------------- GEMM: h = feat @ W^T via split-bf16 MFMA ----------------
// out[n][c] = sum_k feat[n][k] * W[c][k];  A = feat (MxK), B = W^T (KxN)
__global__ __launch_bounds__(256) void k_gemm_mfma(const float* __restrict__ feat,
    const ushort* __restrict__ Whi, const ushort* __restrict__ Wlo,
    float* __restrict__ hout) {
  __shared__ ushort Ahi[128 * 128];  // 32 KB, rows of 16 chunks x 16B, chunk idx XOR row&15
  __shared__ ushort Alo[128 * 128];  // 32 KB
  int n0 = blockIdx.x * 128;
  int t = threadIdx.x;
  {
    int row = t >> 1, half = t & 1;
    int n = n0 + row;
    int sw = row & 15;
    if (n < NN) {
      const float4* src = (const float4*)&feat[(size_t)n * 128 + half * 64];
#pragma unroll
      for (int i = 0; i < 8; i++) {
        float4 a = src[2 * i], b = src[2 * i + 1];
        float vv[8] = {a.x, a.y, a.z, a.w, b.x, b.y, b.z, b.w};
        us8 hh, ll;
#pragma unroll
        for (int j = 0; j < 8; j++) {
          ushort hb = f2bf(vv[j]);
          float hf = __uint_as_float(((unsigned)hb) << 16);
          hh[j] = hb;
          ll[j] = f2bf(vv[j] - hf);
        }
        int pc = (half * 8 + i) ^ sw;
        *(us8*)&Ahi[row * 128 + pc * 8] = hh;
        *(us8*)&Alo[row * 128 + pc * 8] = ll;
      }
    } else {
      us8 z = (us8)0;
#pragma unroll
      for (int i = 0; i < 8; i++) {
        int pc = (half * 8 + i) ^ sw;
        *(us8*)&Ahi[row * 128 + pc * 8] = z;
        *(us8*)&Alo[row * 128 + pc * 8] = z;
      }
    }
  }
  __syncthreads();

  int wave = t >> 6, lane = t & 63;
  int quad = lane >> 4, r16 = lane & 15;
  f32x4 acc[2][8];
#pragma unroll
  for (int mt = 0; mt < 2; mt++)
#pragma unroll
    for (int nt = 0; nt < 8; nt++) acc[mt][nt] = (f32x4)0.f;

  for (int ks = 0; ks < 4; ks++) {
    bf16x8 bh[8], bl[8];
#pragma unroll
    for (int nt = 0; nt < 8; nt++) {
      size_t wo = (size_t)(nt * 16 + r16) * 128 + ks * 32 + quad * 8;
      bh[nt] = *(const bf16x8*)&Whi[wo];
      bl[nt] = *(const bf16x8*)&Wlo[wo];
    }
#pragma unroll
    for (int mt = 0; mt < 2; mt++) {
      int row = wave * 32 + mt * 16 + r16;
      int pc = (ks * 4 + quad) ^ (row & 15);
      bf16x8 ah = *(const bf16x8*)&Ahi[row * 128 + pc * 8];
      bf16x8 al = *(const bf16x8*)&Alo[row * 128 + pc * 8];
#pragma unroll
      for (int nt = 0; nt < 8; nt++) {
        acc[mt][nt] = __builtin_amdgcn_mfma_f32_16x16x32_bf16(ah, bh[nt], acc[mt][nt], 0, 0, 0);
        acc[mt][nt] = __builtin_amdgcn_mfma_f32_16x16x32_bf16(al, bh[nt], acc[mt][nt], 0, 0, 0);
        acc[mt][nt] = __builtin_amdgcn_mfma_f32_16x16x32_bf16(ah, bl[nt], acc[mt][nt], 0, 0, 0);
      }
    }
  }

#pragma unroll
  for (int mt = 0; mt < 2; mt++) {
    int rbase = n0 + wave * 32 + mt * 16 + quad * 4;
#pragma unroll
    for (int reg = 0; reg < 4; reg++) {
      int node = rbase + reg;
      if (node < NN) {
        float* dst = &hout[(size_t)node * 128 + r16];
#pragma unroll
        for (int nt = 0; nt < 8; nt++) dst[nt * 16] = acc[mt][nt][reg];
      }
    }
  }
}

// ---------------- per-node attention logits ----------------
__global__ __launch_bounds__(256) void k_att(const float* __restrict__ h,
    const float* __restrict__ att_s, const float* __restrict__ att_d,
    float* __restrict__ asrc, float* __restrict__ adst) {
  int t = blockIdx.x * 256 + threadIdx.x;
  if (t >= NN * 4) return;
  int n = t >> 2, hd = t & 3;
  const float4* hp = (const float4*)&h[n * 128 + hd * 32];
  const float4* sp = (const float4*)&att_s[hd * 32];
  const float4* dp = (const float4*)&att_d[hd * 32];
  float sa = 0.f, sd = 0.f;
#pragma unroll
  for (int i = 0; i < 8; i++) {
    float4 hv = hp[i], sv = sp[i], dv = dp[i];
    sa += hv.x * sv.x + hv.y * sv.y + hv.z * sv.z + hv.w * sv.w;
    sd += hv.x * dv.x + hv.y * dv.y + hv.z * dv.z + hv.w * dv.w;
  }
  asrc[t] = sa;
  adst[t] = sd;
}

// ---------------- per-edge raw attention (leaky-relu) ----------------
__global__ __launch_bounds__(256) void k_alpha(const int* __restrict__ ei,
    const float4* __restrict__ asrc, const float4* __restrict__ adst,
    float4* __restrict__ alpha) {
  int e = blockIdx.x * 256 + threadIdx.x;
  if (e >= EP) return;
  int s, d;
  if (e < EE) { s = ei[e]; d = ei[EE + e]; } else { s = e - EE; d = s; }
  float4 a = asrc[s], bd = adst[d];
  float4 r; float v;
  v = a.x + bd.x; r.x = v > 0.f ? v : NEG * v;
  v = a.y + bd.y; r.y = v > 0.f ? v : NEG * v;
  v = a.z + bd.z; r.z = v > 0.f ? v : NEG * v;
  v = a.w + bd.w; r.w = v > 0.f ? v : NEG * v;
  alpha[e] = r;
}

// ---------------- per-dst segment softmax + weighted aggregation + bias + ELU ----------------
__global__ __launch_bounds__(64) void k_agg(const float* __restrict__ h,
    const float4* __restrict__ alpha, const int* __restrict__ offs,
    const int* __restrict__ srcs, const int* __restrict__ eids,
    const float* __restrict__ bias, float* __restrict__ outf) {
  int node = blockIdx.x;
  int lane = threadIdx.x;
  int e0 = offs[node], e1 = offs[node + 1];

  float m0 = -1e30f, m1 = -1e30f, m2 = -1e30f, m3 = -1e30f;
  float s0 = 0.f, s1 = 0.f, s2 = 0.f, s3 = 0.f;
  for (int j = e0 + lane; j < e1; j += 64) {
    float4 a = alpha[eids[j]];
    float nm;
    nm = fmaxf(m0, a.x); s0 = s0 * expf(m0 - nm) + expf(a.x - nm); m0 = nm;
    nm = fmaxf(m1, a.y); s1 = s1 * expf(m1 - nm) + expf(a.y - nm); m1 = nm;
    nm = fmaxf(m2, a.z); s2 = s2 * expf(m2 - nm) + expf(a.z - nm); m2 = nm;
    nm = fmaxf(m3, a.w); s3 = s3 * expf(m3 - nm) + expf(a.w - nm); m3 = nm;
  }
#pragma unroll
  for (int off = 32; off > 0; off >>= 1) {
    float om, os, nm;
    om = __shfl_xor(m0, off); os = __shfl_xor(s0, off);
    nm = fmaxf(m0, om); s0 = s0 * expf(m0 - nm) + os * expf(om - nm); m0 = nm;
    om = __shfl_xor(m1, off); os = __shfl_xor(s1, off);
    nm = fmaxf(m1, om); s1 = s1 * expf(m1 - nm) + os * expf(om - nm); m1 = nm;
    om = __shfl_xor(m2, off); os = __shfl_xor(s2, off);
    nm = fmaxf(m2, om); s2 = s2 * expf(m2 - nm) + os * expf(om - nm); m2 = nm;
    om = __shfl_xor(m3, off); os = __shfl_xor(s3, off);
    nm = fmaxf(m3, om); s3 = s3 * expf(m3 - nm) + os * expf(om - nm); m3 = nm;
  }
  float r0 = 1.0f / (s0 + 1e-16f);
  float r1 = 1.0f / (s1 + 1e-16f);
  float r2 = 1.0f / (s2 + 1e-16f);
  float r3 = 1.0f / (s3 + 1e-16f);

  int head = lane >> 4;
  __shared__ int s_src[64];
  __shared__ float s_w[64 * 4];
  float accx = 0.f, accy = 0.f;
  for (int base = e0; base < e1; base += 64) {
    __syncthreads();
    int j = base + lane;
    if (j < e1) {
      s_src[lane] = srcs[j];
      float4 a = alpha[eids[j]];
      s_w[lane * 4 + 0] = expf(a.x - m0) * r0;
      s_w[lane * 4 + 1] = expf(a.y - m1) * r1;
      s_w[lane * 4 + 2] = expf(a.z - m2) * r2;
      s_w[lane * 4 + 3] = expf(a.w - m3) * r3;
    }
    __syncthreads();
    int cnt = min(64, e1 - base);
    for (int k = 0; k < cnt; k++) {
      int sn = s_src[k];
      float w = s_w[(k << 2) + head];
      float2 hv = *(const float2*)&h[sn * 128 + (lane << 1)];
      accx = fmaf(w, hv.x, accx);
      accy = fmaf(w, hv.y, accy);
    }
  }
  int c0 = lane << 1;
  float o0 = accx + bias[c0];
  float o1 = accy + bias[c0 + 1];
  o0 = o0 > 0.f ? o0 : expm1f(o0);
  o1 = o1 > 0.f ? o1 : expm1f(o1);
  float2 o = make_float2(o0, o1);
  *(float2*)&outf[node * 128 + c0] = o;
}

// ---------------- mean pool ----------------
__global__ __launch_bounds__(128) void k_pool(const float* __restrict__ feat,
    const int* __restrict__ batch, float* __restrict__ pooled, float* __restrict__ cnt) {
  int n0 = blockIdx.x * 32;
  int c = threadIdx.x;
  float acc = 0.f; int curg = -1;
  for (int i = 0; i < 32; i++) {
    int n = n0 + i;
    if (n >= NN) break;
    int g = batch[n];
    if (g != curg) {
      if (curg >= 0) atomicAdd(&pooled[curg * 128 + c], acc);
      acc = 0.f; curg = g;
    }
    acc += feat[n * 128 + c];
  }
  if (curg >= 0) atomicAdd(&pooled[curg * 128 + c], acc);
  if (threadIdx.x == 0) {
    float cc = 0.f; int cg = -1;
    for (int i = 0; i < 32; i++) {
      int n = n0 + i;
      if (n >= NN) break;
      int g = batch[n];
      if (g != cg) { if (cg >= 0) atomicAdd(&cnt[cg], cc); cc = 0.f; cg = g; }
      cc += 1.f;
    }
    if (cg >= 0) atomicAdd(&cnt[cg], cc);
  }
}

// ---------------- final FC ----------------
__global__ __launch_bounds__(128) void k_fc(const float* __restrict__ pooled,
    const float* __restrict__ cnt, const float* __restrict__ fcW,
    const float* __restrict__ fcb, float* __restrict__ out) {
  int g = blockIdx.x;
  __shared__ float p[128];
  int t = threadIdx.x;
  float inv = 1.0f / fmaxf(cnt[g], 1.0f);
  p[t] = pooled[g * 128 + t] * inv;
  __syncthreads();
  if (t < OUTC) {
    float acc = fcb[t];
    const float4* wr = (const float4*)&fcW[t * 128];
    const float4* pp = (const float4*)p;
#pragma unroll
    for (int i = 0; i < 32; i++) {
      float4 w = wr[i], pv = pp[i];
      acc = fmaf(w.x, pv.x, fmaf(w.y, pv.y, fmaf(w.z, pv.z, fmaf(w.w, pv.w, acc))));
    }
    out[g * OUTC + t] = acc;
  }
}

extern "C" void kernel_launch(void* const* d_in, const int* in_sizes, int n_in,
                              void* d_out, int out_size, void* d_ws, size_t ws_size,
                              hipStream_t stream) {
  const float* x    = (const float*)d_in[0];
  const int*   ei   = (const int*)d_in[1];
  const int*   batch= (const int*)d_in[2];
  const float* W1   = (const float*)d_in[3];
  const float* as1  = (const float*)d_in[4];
  const float* ad1  = (const float*)d_in[5];
  const float* b1   = (const float*)d_in[6];
  const float* W2   = (const float*)d_in[7];
  const float* as2  = (const float*)d_in[8];
  const float* ad2  = (const float*)d_in[9];
  const float* b2   = (const float*)d_in[10];
  const float* W3   = (const float*)d_in[11];
  const float* as3  = (const float*)d_in[12];
  const float* ad3  = (const float*)d_in[13];
  const float* b3   = (const float*)d_in[14];
  const float* fcW  = (const float*)d_in[15];
  const float* fcb  = (const float*)d_in[16];
  float* out = (float*)d_out;

  char* p = (char*)d_ws;
  auto alloc = [&](size_t bytes) { char* r = p; p += (bytes + 255) & ~(size_t)255; return r; };
  float* h      = (float*)alloc((size_t)NN * 128 * 4);
  float* buf0   = (float*)alloc((size_t)NN * 128 * 4);
  float* asrc   = (float*)alloc((size_t)NN * 4 * 4);
  float* adst   = (float*)alloc((size_t)NN * 4 * 4);
  float* alpha  = (float*)alloc((size_t)EP * 4 * 4);
  int*   deg    = (int*)alloc((size_t)NN * 4);
  int*   offs   = (int*)alloc((size_t)(NN + 1) * 4);
  int*   cursor = (int*)alloc((size_t)NN * 4);
  int*   srcs   = (int*)alloc((size_t)EP * 4);
  int*   eids   = (int*)alloc((size_t)EP * 4);
  float* pooled = (float*)alloc((size_t)GG * 128 * 4);
  float* cnt    = (float*)alloc((size_t)GG * 4);
  ushort* whi[3], *wlo[3];
  for (int l = 0; l < 3; l++) {
    whi[l] = (ushort*)alloc(128 * 128 * 2);
    wlo[l] = (ushort*)alloc(128 * 128 * 2);
  }

  hipMemsetAsync(deg, 0, (size_t)NN * 4, stream);
  hipMemsetAsync(cursor, 0, (size_t)NN * 4, stream);
  hipMemsetAsync(pooled, 0, (size_t)GG * 128 * 4, stream);
  hipMemsetAsync(cnt, 0, (size_t)GG * 4, stream);

  k_hist<<<(EP + 255) / 256, 256, 0, stream>>>(ei, deg);
  k_scan<<<1, 1024, 0, stream>>>(deg, offs);
  k_scatter<<<(EP + 255) / 256, 256, 0, stream>>>(ei, offs, cursor, srcs, eids);

  const float* Ws[3]  = {W1, W2, W3};
  const float* ass[3] = {as1, as2, as3};
  const float* ads[3] = {ad1, ad2, ad3};
  const float* bs[3]  = {b1, b2, b3};
  for (int l = 0; l < 3; l++)
    k_split<<<64, 256, 0, stream>>>(Ws[l], whi[l], wlo[l]);

  const float* fin = x;
  for (int l = 0; l < 3; l++) {
    k_gemm_mfma<<<(NN + 127) / 128, 256, 0, stream>>>(fin, whi[l], wlo[l], h);
    k_att<<<(NN * 4 + 255) / 256, 256, 0, stream>>>(h, ass[l], ads[l], asrc, adst);
    k_alpha<<<(EP + 255) / 256, 256, 0, stream>>>(ei, (const float4*)asrc, (const float4*)adst, (float4*)alpha);
    k_agg<<<NN, 64, 0, stream>>>(h, (const float4*)alpha, offs, srcs, eids, bs[l], buf0);
    fin = buf0;
  }
  k_pool<<<(NN + 31) / 32, 128, 0, stream>>>(buf0, batch, pooled, cnt);
  k_fc<<<GG, 128, 0, stream>>>(pooled, cnt, fcW, fcb, out);
}

// Round 3
// 584.072 us; speedup vs baseline: 1.7160x; 1.2292x over previous
//
#include <hip/hip_runtime.h>
#include <math.h>

#define NN 50000
#define EE 800000
#define EP (EE + NN)
#define GG 512
#define OUTC 100
#define NEG 0.2f

typedef __attribute__((ext_vector_type(8))) short bf16x8;
typedef __attribute__((ext_vector_type(8))) unsigned short us8;
typedef __attribute__((ext_vector_type(4))) float f32x4;

__device__ inline ushort f2bf(float v) {
  unsigned u = __float_as_uint(v);
  unsigned r = (u + 0x7fff + ((u >> 16) & 1)) >> 16;
  return (ushort)r;
}

// ---------------- CSR build ----------------
__global__ __launch_bounds__(256) void k_hist(const int* __restrict__ ei, int* __restrict__ deg) {
  int e = blockIdx.x * 256 + threadIdx.x;
  if (e >= EP) return;
  int d = (e < EE) ? ei[EE + e] : (e - EE);
  atomicAdd(&deg[d], 1);
}

// 3-stage scan: partial per-block inclusive scan -> scan of block sums -> add prefix
__global__ __launch_bounds__(256) void k_scan1(const int* __restrict__ deg,
    int* __restrict__ part, int* __restrict__ bsum) {
  __shared__ int tmp[256];
  int i = blockIdx.x * 256 + threadIdx.x;
  int v = (i < NN) ? deg[i] : 0;
  tmp[threadIdx.x] = v;
  __syncthreads();
  for (int off = 1; off < 256; off <<= 1) {
    int t = (threadIdx.x >= off) ? tmp[threadIdx.x - off] : 0;
    __syncthreads();
    tmp[threadIdx.x] += t;
    __syncthreads();
  }
  if (i < NN) part[i] = tmp[threadIdx.x];
  if (threadIdx.x == 255) bsum[blockIdx.x] = tmp[255];
}

__global__ __launch_bounds__(256) void k_scan2(int* __restrict__ bsum, int nb) {
  __shared__ int tmp[256];
  int v = (threadIdx.x < nb) ? bsum[threadIdx.x] : 0;
  tmp[threadIdx.x] = v;
  __syncthreads();
  for (int off = 1; off < 256; off <<= 1) {
    int t = (threadIdx.x >= off) ? tmp[threadIdx.x - off] : 0;
    __syncthreads();
    tmp[threadIdx.x] += t;
    __syncthreads();
  }
  if (threadIdx.x < nb) bsum[threadIdx.x] = tmp[threadIdx.x];
}

__global__ __launch_bounds__(256) void k_scan3(const int* __restrict__ part,
    const int* __restrict__ bsum, int* __restrict__ offs) {
  int i = blockIdx.x * 256 + threadIdx.x;
  if (i < NN) {
    int prefix = (blockIdx.x > 0) ? bsum[blockIdx.x - 1] : 0;
    offs[i + 1] = part[i] + prefix;
  }
  if (i == 0) offs[0] = 0;
}

__global__ __launch_bounds__(256) void k_scatter(const int* __restrict__ ei,
    const int* __restrict__ offs, int* __restrict__ cursor, int* __restrict__ srcs) {
  int e = blockIdx.x * 256 + threadIdx.x;
  if (e >= EP) return;
  int s, d;
  if (e < EE) { s = ei[e]; d = ei[EE + e]; } else { s = e - EE; d = s; }
  int pos = offs[d] + atomicAdd(&cursor[d], 1);
  srcs[pos] = s;
}

// ---------------- split W (fp32 -> bf16 hi/lo), 128x128 ----------------
__global__ __launch_bounds__(256) void k_split(const float* __restrict__ W,
    ushort* __restrict__ hi, ushort* __restrict__ lo) {
  int i = blockIdx.x * 256 + threadIdx.x;
  if (i >= 128 * 128) return;
  float v = W[i];
  ushort hb = f2bf(v);
  float hf = __uint_as_float(((unsigned)hb) << 16);
  hi[i] = hb;
  lo[i] = f2bf(v - hf);
}

// ---------------- GEMM: h = feat @ W^T via split-bf16 MFMA ----------------
__global__ __launch_bounds__(256) void k_gemm_mfma(const float* __restrict__ feat,
    const ushort* __restrict__ Whi, const ushort* __restrict__ Wlo,
    float* __restrict__ hout) {
  __shared__ ushort Ahi[128 * 128];
  __shared__ ushort Alo[128 * 128];
  int n0 = blockIdx.x * 128;
  int t = threadIdx.x;
  {
    int row = t >> 1, half = t & 1;
    int n = n0 + row;
    int sw = row & 15;
    if (n < NN) {
      const float4* src = (const float4*)&feat[(size_t)n * 128 + half * 64];
#pragma unroll
      for (int i = 0; i < 8; i++) {
        float4 a = src[2 * i], b = src[2 * i + 1];
        float vv[8] = {a.x, a.y, a.z, a.w, b.x, b.y, b.z, b.w};
        us8 hh, ll;
#pragma unroll
        for (int j = 0; j < 8; j++) {
          ushort hb = f2bf(vv[j]);
          float hf = __uint_as_float(((unsigned)hb) << 16);
          hh[j] = hb;
          ll[j] = f2bf(vv[j] - hf);
        }
        int pc = (half * 8 + i) ^ sw;
        *(us8*)&Ahi[row * 128 + pc * 8] = hh;
        *(us8*)&Alo[row * 128 + pc * 8] = ll;
      }
    } else {
      us8 z = (us8)0;
#pragma unroll
      for (int i = 0; i < 8; i++) {
        int pc = (half * 8 + i) ^ sw;
        *(us8*)&Ahi[row * 128 + pc * 8] = z;
        *(us8*)&Alo[row * 128 + pc * 8] = z;
      }
    }
  }
  __syncthreads();

  int wave = t >> 6, lane = t & 63;
  int quad = lane >> 4, r16 = lane & 15;
  f32x4 acc[2][8];
#pragma unroll
  for (int mt = 0; mt < 2; mt++)
#pragma unroll
    for (int nt = 0; nt < 8; nt++) acc[mt][nt] = (f32x4)0.f;

  for (int ks = 0; ks < 4; ks++) {
    bf16x8 bh[8], bl[8];
#pragma unroll
    for (int nt = 0; nt < 8; nt++) {
      size_t wo = (size_t)(nt * 16 + r16) * 128 + ks * 32 + quad * 8;
      bh[nt] = *(const bf16x8*)&Whi[wo];
      bl[nt] = *(const bf16x8*)&Wlo[wo];
    }
#pragma unroll
    for (int mt = 0; mt < 2; mt++) {
      int row = wave * 32 + mt * 16 + r16;
      int pc = (ks * 4 + quad) ^ (row & 15);
      bf16x8 ah = *(const bf16x8*)&Ahi[row * 128 + pc * 8];
      bf16x8 al = *(const bf16x8*)&Alo[row * 128 + pc * 8];
#pragma unroll
      for (int nt = 0; nt < 8; nt++) {
        acc[mt][nt] = __builtin_amdgcn_mfma_f32_16x16x32_bf16(ah, bh[nt], acc[mt][nt], 0, 0, 0);
        acc[mt][nt] = __builtin_amdgcn_mfma_f32_16x16x32_bf16(al, bh[nt], acc[mt][nt], 0, 0, 0);
        acc[mt][nt] = __builtin_amdgcn_mfma_f32_16x16x32_bf16(ah, bl[nt], acc[mt][nt], 0, 0, 0);
      }
    }
  }

#pragma unroll
  for (int mt = 0; mt < 2; mt++) {
    int rbase = n0 + wave * 32 + mt * 16 + quad * 4;
#pragma unroll
    for (int reg = 0; reg < 4; reg++) {
      int node = rbase + reg;
      if (node < NN) {
        float* dst = &hout[(size_t)node * 128 + r16];
#pragma unroll
        for (int nt = 0; nt < 8; nt++) dst[nt * 16] = acc[mt][nt][reg];
      }
    }
  }
}

// ---------------- per-node attention logits ----------------
__global__ __launch_bounds__(256) void k_att(const float* __restrict__ h,
    const float* __restrict__ att_s, const float* __restrict__ att_d,
    float* __restrict__ asrc, float* __restrict__ adst) {
  int t = blockIdx.x * 256 + threadIdx.x;
  if (t >= NN * 4) return;
  int n = t >> 2, hd = t & 3;
  const float4* hp = (const float4*)&h[n * 128 + hd * 32];
  const float4* sp = (const float4*)&att_s[hd * 32];
  const float4* dp = (const float4*)&att_d[hd * 32];
  float sa = 0.f, sd = 0.f;
#pragma unroll
  for (int i = 0; i < 8; i++) {
    float4 hv = hp[i], sv = sp[i], dv = dp[i];
    sa += hv.x * sv.x + hv.y * sv.y + hv.z * sv.z + hv.w * sv.w;
    sd += hv.x * dv.x + hv.y * dv.y + hv.z * dv.z + hv.w * dv.w;
  }
  asrc[t] = sa;
  adst[t] = sd;
}

// ---------------- per-node softmax stats: 16 lanes per node, 16 nodes per block ----------------
__global__ __launch_bounds__(256) void k_stats(const float4* __restrict__ asrc,
    const float4* __restrict__ adst, const int* __restrict__ offs,
    const int* __restrict__ srcs, float4* __restrict__ mbuf, float4* __restrict__ rbuf) {
  int g = threadIdx.x >> 4, gl = threadIdx.x & 15;
  int node = blockIdx.x * 16 + g;
  if (node >= NN) return;
  int e0 = offs[node], e1 = offs[node + 1];
  float4 ad = adst[node];
  float m0 = -1e30f, m1 = -1e30f, m2 = -1e30f, m3 = -1e30f;
  float s0 = 0.f, s1 = 0.f, s2 = 0.f, s3 = 0.f;
  for (int j = e0 + gl; j < e1; j += 16) {
    float4 a = asrc[srcs[j]];
    float v, nm;
    v = a.x + ad.x; v = v > 0.f ? v : NEG * v;
    nm = fmaxf(m0, v); s0 = s0 * expf(m0 - nm) + expf(v - nm); m0 = nm;
    v = a.y + ad.y; v = v > 0.f ? v : NEG * v;
    nm = fmaxf(m1, v); s1 = s1 * expf(m1 - nm) + expf(v - nm); m1 = nm;
    v = a.z + ad.z; v = v > 0.f ? v : NEG * v;
    nm = fmaxf(m2, v); s2 = s2 * expf(m2 - nm) + expf(v - nm); m2 = nm;
    v = a.w + ad.w; v = v > 0.f ? v : NEG * v;
    nm = fmaxf(m3, v); s3 = s3 * expf(m3 - nm) + expf(v - nm); m3 = nm;
  }
#pragma unroll
  for (int off = 1; off < 16; off <<= 1) {
    float om, os, nm;
    om = __shfl_xor(m0, off); os = __shfl_xor(s0, off);
    nm = fmaxf(m0, om); s0 = s0 * expf(m0 - nm) + os * expf(om - nm); m0 = nm;
    om = __shfl_xor(m1, off); os = __shfl_xor(s1, off);
    nm = fmaxf(m1, om); s1 = s1 * expf(m1 - nm) + os * expf(om - nm); m1 = nm;
    om = __shfl_xor(m2, off); os = __shfl_xor(s2, off);
    nm = fmaxf(m2, om); s2 = s2 * expf(m2 - nm) + os * expf(om - nm); m2 = nm;
    om = __shfl_xor(m3, off); os = __shfl_xor(s3, off);
    nm = fmaxf(m3, om); s3 = s3 * expf(m3 - nm) + os * expf(om - nm); m3 = nm;
  }
  if (gl == 0) {
    mbuf[node] = make_float4(m0, m1, m2, m3);
    rbuf[node] = make_float4(1.f / (s0 + 1e-16f), 1.f / (s1 + 1e-16f),
                             1.f / (s2 + 1e-16f), 1.f / (s3 + 1e-16f));
  }
}

// ---------------- gather-aggregate: 4 waves/block, 1 node/wave, 2 edges/iter ----------------
__global__ __launch_bounds__(256) void k_gather(const float* __restrict__ h,
    const float4* __restrict__ asrc, const float4* __restrict__ adst,
    const float4* __restrict__ mbuf, const float4* __restrict__ rbuf,
    const int* __restrict__ offs, const int* __restrict__ srcs,
    const float* __restrict__ bias, float* __restrict__ outf) {
  __shared__ int s_src[4][64];
  __shared__ float4 s_w[4][64];
  __shared__ int s_mc[4];

  int wave = threadIdx.x >> 6, lane = threadIdx.x & 63;
  int node = blockIdx.x * 4 + wave;
  int e0 = 0, e1 = 0;
  float4 ad = make_float4(0.f, 0.f, 0.f, 0.f), mm = ad, rr = ad;
  if (node < NN) {
    e0 = offs[node]; e1 = offs[node + 1];
    ad = adst[node]; mm = mbuf[node]; rr = rbuf[node];
  }
  if (lane == 0) s_mc[wave] = (e1 - e0 + 63) >> 6;
  __syncthreads();
  int maxc = max(max(s_mc[0], s_mc[1]), max(s_mc[2], s_mc[3]));

  int half = lane >> 5;       // which of the 2 edges per iter
  int cl = lane & 31;         // channel lane
  int c0 = cl << 2;           // 4 channels per lane
  int head = cl >> 3;
  float4 acc = make_float4(0.f, 0.f, 0.f, 0.f);

  for (int c = 0; c < maxc; c++) {
    int base = e0 + (c << 6);
    __syncthreads();
    int j = base + lane;
    if (j < e1) {
      int sn = srcs[j];
      float4 a = asrc[sn];
      float v;
      float4 w;
      v = a.x + ad.x; v = v > 0.f ? v : NEG * v; w.x = expf(v - mm.x) * rr.x;
      v = a.y + ad.y; v = v > 0.f ? v : NEG * v; w.y = expf(v - mm.y) * rr.y;
      v = a.z + ad.z; v = v > 0.f ? v : NEG * v; w.z = expf(v - mm.z) * rr.z;
      v = a.w + ad.w; v = v > 0.f ? v : NEG * v; w.w = expf(v - mm.w) * rr.w;
      s_src[wave][lane] = sn << 7;   // row byte-offset base (in floats: sn*128)
      s_w[wave][lane] = w;
    } else {
      s_src[wave][lane] = 0;
      s_w[wave][lane] = make_float4(0.f, 0.f, 0.f, 0.f);
    }
    __syncthreads();
    int cnt = min(64, e1 - base);
    for (int k = 0; k < cnt; k += 2) {
      int e = k + half;
      int ro = s_src[wave][e];
      float w = ((const float*)&s_w[wave][e])[head];
      float4 hv = *(const float4*)&h[ro + c0];
      acc.x = fmaf(w, hv.x, acc.x);
      acc.y = fmaf(w, hv.y, acc.y);
      acc.z = fmaf(w, hv.z, acc.z);
      acc.w = fmaf(w, hv.w, acc.w);
    }
  }

  // combine the two edge-halves: lane i and lane i+32 hold the same channels
  acc.x += __shfl_xor(acc.x, 32);
  acc.y += __shfl_xor(acc.y, 32);
  acc.z += __shfl_xor(acc.z, 32);
  acc.w += __shfl_xor(acc.w, 32);

  if (half == 0 && node < NN) {
    float4 b = *(const float4*)&bias[c0];
    float o0 = acc.x + b.x, o1 = acc.y + b.y, o2 = acc.z + b.z, o3 = acc.w + b.w;
    o0 = o0 > 0.f ? o0 : expm1f(o0);
    o1 = o1 > 0.f ? o1 : expm1f(o1);
    o2 = o2 > 0.f ? o2 : expm1f(o2);
    o3 = o3 > 0.f ? o3 : expm1f(o3);
    *(float4*)&outf[(size_t)node * 128 + c0] = make_float4(o0, o1, o2, o3);
  }
}

// ---------------- mean pool ----------------
__global__ __launch_bounds__(128) void k_pool(const float* __restrict__ feat,
    const int* __restrict__ batch, float* __restrict__ pooled, float* __restrict__ cnt) {
  int n0 = blockIdx.x * 32;
  int c = threadIdx.x;
  float acc = 0.f; int curg = -1;
  for (int i = 0; i < 32; i++) {
    int n = n0 + i;
    if (n >= NN) break;
    int g = batch[n];
    if (g != curg) {
      if (curg >= 0) atomicAdd(&pooled[curg * 128 + c], acc);
      acc = 0.f; curg = g;
    }
    acc += feat[n * 128 + c];
  }
  if (curg >= 0) atomicAdd(&pooled[curg * 128 + c], acc);
  if (threadIdx.x == 0) {
    float cc = 0.f; int cg = -1;
    for (int i = 0; i < 32; i++) {
      int n = n0 + i;
      if (n >= NN) break;
      int g = batch[n];
      if (g != cg) { if (cg >= 0) atomicAdd(&cnt[cg], cc); cc = 0.f; cg = g; }
      cc += 1.f;
    }
    if (cg >= 0) atomicAdd(&cnt[cg], cc);
  }
}

// ---------------- final FC ----------------
__global__ __launch_bounds__(128) void k_fc(const float* __restrict__ pooled,
    const float* __restrict__ cnt, const float* __restrict__ fcW,
    const float* __restrict__ fcb, float* __restrict__ out) {
  int g = blockIdx.x;
  __shared__ float p[128];
  int t = threadIdx.x;
  float inv = 1.0f / fmaxf(cnt[g], 1.0f);
  p[t] = pooled[g * 128 + t] * inv;
  __syncthreads();
  if (t < OUTC) {
    float acc = fcb[t];
    const float4* wr = (const float4*)&fcW[t * 128];
    const float4* pp = (const float4*)p;
#pragma unroll
    for (int i = 0; i < 32; i++) {
      float4 w = wr[i], pv = pp[i];
      acc = fmaf(w.x, pv.x, fmaf(w.y, pv.y, fmaf(w.z, pv.z, fmaf(w.w, pv.w, acc))));
    }
    out[g * OUTC + t] = acc;
  }
}

extern "C" void kernel_launch(void* const* d_in, const int* in_sizes, int n_in,
                              void* d_out, int out_size, void* d_ws, size_t ws_size,
                              hipStream_t stream) {
  const float* x    = (const float*)d_in[0];
  const int*   ei   = (const int*)d_in[1];
  const int*   batch= (const int*)d_in[2];
  const float* W1   = (const float*)d_in[3];
  const float* as1  = (const float*)d_in[4];
  const float* ad1  = (const float*)d_in[5];
  const float* b1   = (const float*)d_in[6];
  const float* W2   = (const float*)d_in[7];
  const float* as2  = (const float*)d_in[8];
  const float* ad2  = (const float*)d_in[9];
  const float* b2   = (const float*)d_in[10];
  const float* W3   = (const float*)d_in[11];
  const float* as3  = (const float*)d_in[12];
  const float* ad3  = (const float*)d_in[13];
  const float* b3   = (const float*)d_in[14];
  const float* fcW  = (const float*)d_in[15];
  const float* fcb  = (const float*)d_in[16];
  float* out = (float*)d_out;

  char* p = (char*)d_ws;
  auto alloc = [&](size_t bytes) { char* r = p; p += (bytes + 255) & ~(size_t)255; return r; };
  float* h      = (float*)alloc((size_t)NN * 128 * 4);
  float* buf0   = (float*)alloc((size_t)NN * 128 * 4);
  float* asrc   = (float*)alloc((size_t)NN * 4 * 4);
  float* adst   = (float*)alloc((size_t)NN * 4 * 4);
  float* mbuf   = (float*)alloc((size_t)NN * 4 * 4);
  float* rbuf   = (float*)alloc((size_t)NN * 4 * 4);
  int*   deg    = (int*)alloc((size_t)NN * 4);
  int*   part   = (int*)alloc((size_t)NN * 4);
  int*   bsum   = (int*)alloc(256 * 4);
  int*   offs   = (int*)alloc((size_t)(NN + 1) * 4);
  int*   cursor = (int*)alloc((size_t)NN * 4);
  int*   srcs   = (int*)alloc((size_t)EP * 4);
  float* pooled = (float*)alloc((size_t)GG * 128 * 4);
  float* cnt    = (float*)alloc((size_t)GG * 4);
  ushort* whi[3], *wlo[3];
  for (int l = 0; l < 3; l++) {
    whi[l] = (ushort*)alloc(128 * 128 * 2);
    wlo[l] = (ushort*)alloc(128 * 128 * 2);
  }

  hipMemsetAsync(deg, 0, (size_t)NN * 4, stream);
  hipMemsetAsync(cursor, 0, (size_t)NN * 4, stream);
  hipMemsetAsync(pooled, 0, (size_t)GG * 128 * 4, stream);
  hipMemsetAsync(cnt, 0, (size_t)GG * 4, stream);

  int nb = (NN + 255) / 256;
  k_hist<<<(EP + 255) / 256, 256, 0, stream>>>(ei, deg);
  k_scan1<<<nb, 256, 0, stream>>>(deg, part, bsum);
  k_scan2<<<1, 256, 0, stream>>>(bsum, nb);
  k_scan3<<<nb, 256, 0, stream>>>(part, bsum, offs);
  k_scatter<<<(EP + 255) / 256, 256, 0, stream>>>(ei, offs, cursor, srcs);

  const float* Ws[3]  = {W1, W2, W3};
  const float* ass[3] = {as1, as2, as3};
  const float* ads[3] = {ad1, ad2, ad3};
  const float* bs[3]  = {b1, b2, b3};
  for (int l = 0; l < 3; l++)
    k_split<<<64, 256, 0, stream>>>(Ws[l], whi[l], wlo[l]);

  const float* fin = x;
  for (int l = 0; l < 3; l++) {
    k_gemm_mfma<<<(NN + 127) / 128, 256, 0, stream>>>(fin, whi[l], wlo[l], h);
    k_att<<<(NN * 4 + 255) / 256, 256, 0, stream>>>(h, ass[l], ads[l], asrc, adst);
    k_stats<<<(NN + 15) / 16, 256, 0, stream>>>((const float4*)asrc, (const float4*)adst,
                                                offs, srcs, (float4*)mbuf, (float4*)rbuf);
    k_gather<<<(NN + 3) / 4, 256, 0, stream>>>(h, (const float4*)asrc, (const float4*)adst,
                                               (const float4*)mbuf, (const float4*)rbuf,
                                               offs, srcs, bs[l], buf0);
    fin = buf0;
  }
  k_pool<<<(NN + 31) / 32, 128, 0, stream>>>(buf0, batch, pooled, cnt);
  k_fc<<<GG, 128, 0, stream>>>(pooled, cnt, fcW, fcb, out);
}

// Round 4
// 508.950 us; speedup vs baseline: 1.9693x; 1.1476x over previous
//
#include <hip/hip_runtime.h>
#include <math.h>

#define NN 50000
#define EE 800000
#define EP (EE + NN)
#define GG 512
#define OUTC 100
#define NEG 0.2f

typedef __attribute__((ext_vector_type(8))) short bf16x8;
typedef __attribute__((ext_vector_type(8))) unsigned short us8;
typedef __attribute__((ext_vector_type(4))) float f32x4;
typedef __attribute__((ext_vector_type(4))) short s16x4;

__device__ inline ushort f2bf(float v) {
  unsigned u = __float_as_uint(v);
  unsigned r = (u + 0x7fff + ((u >> 16) & 1)) >> 16;
  return (ushort)r;
}

// ---------------- CSR build ----------------
__global__ __launch_bounds__(256) void k_hist(const int* __restrict__ ei, int* __restrict__ deg) {
  int e = blockIdx.x * 256 + threadIdx.x;
  if (e >= EP) return;
  int d = (e < EE) ? ei[EE + e] : (e - EE);
  atomicAdd(&deg[d], 1);
}

__global__ __launch_bounds__(256) void k_scan1(const int* __restrict__ deg,
    int* __restrict__ part, int* __restrict__ bsum) {
  __shared__ int tmp[256];
  int i = blockIdx.x * 256 + threadIdx.x;
  int v = (i < NN) ? deg[i] : 0;
  tmp[threadIdx.x] = v;
  __syncthreads();
  for (int off = 1; off < 256; off <<= 1) {
    int t = (threadIdx.x >= off) ? tmp[threadIdx.x - off] : 0;
    __syncthreads();
    tmp[threadIdx.x] += t;
    __syncthreads();
  }
  if (i < NN) part[i] = tmp[threadIdx.x];
  if (threadIdx.x == 255) bsum[blockIdx.x] = tmp[255];
}

__global__ __launch_bounds__(256) void k_scan2(int* __restrict__ bsum, int nb) {
  __shared__ int tmp[256];
  int v = (threadIdx.x < nb) ? bsum[threadIdx.x] : 0;
  tmp[threadIdx.x] = v;
  __syncthreads();
  for (int off = 1; off < 256; off <<= 1) {
    int t = (threadIdx.x >= off) ? tmp[threadIdx.x - off] : 0;
    __syncthreads();
    tmp[threadIdx.x] += t;
    __syncthreads();
  }
  if (threadIdx.x < nb) bsum[threadIdx.x] = tmp[threadIdx.x];
}

__global__ __launch_bounds__(256) void k_scan3(const int* __restrict__ part,
    const int* __restrict__ bsum, int* __restrict__ offs) {
  int i = blockIdx.x * 256 + threadIdx.x;
  if (i < NN) {
    int prefix = (blockIdx.x > 0) ? bsum[blockIdx.x - 1] : 0;
    offs[i + 1] = part[i] + prefix;
  }
  if (i == 0) offs[0] = 0;
}

__global__ __launch_bounds__(256) void k_scatter(const int* __restrict__ ei,
    const int* __restrict__ offs, int* __restrict__ cursor, int* __restrict__ srcs) {
  int e = blockIdx.x * 256 + threadIdx.x;
  if (e >= EP) return;
  int s, d;
  if (e < EE) { s = ei[e]; d = ei[EE + e]; } else { s = e - EE; d = s; }
  int pos = offs[d] + atomicAdd(&cursor[d], 1);
  srcs[pos] = s;
}

// ---------------- split W (fp32 -> bf16 hi/lo), 128x128 ----------------
__global__ __launch_bounds__(256) void k_split(const float* __restrict__ W,
    ushort* __restrict__ hi, ushort* __restrict__ lo) {
  int i = blockIdx.x * 256 + threadIdx.x;
  if (i >= 128 * 128) return;
  float v = W[i];
  ushort hb = f2bf(v);
  float hf = __uint_as_float(((unsigned)hb) << 16);
  hi[i] = hb;
  lo[i] = f2bf(v - hf);
}

// ---------------- GEMM + fused attention-logits + int16 row quantization ----------------
// out row: hq[n][c] = round(h[n][c]*32767/rowmax), scalef[n] = rowmax/32767
// asrc[n] = per-head dot(h, att_src), adst[n] = per-head dot(h, att_dst)
__global__ __launch_bounds__(256) void k_gemm_mfma(const float* __restrict__ feat,
    const ushort* __restrict__ Whi, const ushort* __restrict__ Wlo,
    const float* __restrict__ att_s, const float* __restrict__ att_d,
    short* __restrict__ hq, float* __restrict__ scalef,
    float4* __restrict__ asrc4, float4* __restrict__ adst4) {
  __shared__ ushort Ahi[128 * 128];
  __shared__ ushort Alo[128 * 128];
  int n0 = blockIdx.x * 128;
  int t = threadIdx.x;
  {
    int row = t >> 1, half = t & 1;
    int n = n0 + row;
    int sw = row & 15;
    if (n < NN) {
      const float4* src = (const float4*)&feat[(size_t)n * 128 + half * 64];
#pragma unroll
      for (int i = 0; i < 8; i++) {
        float4 a = src[2 * i], b = src[2 * i + 1];
        float vv[8] = {a.x, a.y, a.z, a.w, b.x, b.y, b.z, b.w};
        us8 hh, ll;
#pragma unroll
        for (int j = 0; j < 8; j++) {
          ushort hb = f2bf(vv[j]);
          float hf = __uint_as_float(((unsigned)hb) << 16);
          hh[j] = hb;
          ll[j] = f2bf(vv[j] - hf);
        }
        int pc = (half * 8 + i) ^ sw;
        *(us8*)&Ahi[row * 128 + pc * 8] = hh;
        *(us8*)&Alo[row * 128 + pc * 8] = ll;
      }
    } else {
      us8 z = (us8)0;
#pragma unroll
      for (int i = 0; i < 8; i++) {
        int pc = (half * 8 + i) ^ sw;
        *(us8*)&Ahi[row * 128 + pc * 8] = z;
        *(us8*)&Alo[row * 128 + pc * 8] = z;
      }
    }
  }
  __syncthreads();

  int wave = t >> 6, lane = t & 63;
  int quad = lane >> 4, r16 = lane & 15;
  f32x4 acc[2][8];
#pragma unroll
  for (int mt = 0; mt < 2; mt++)
#pragma unroll
    for (int nt = 0; nt < 8; nt++) acc[mt][nt] = (f32x4)0.f;

  for (int ks = 0; ks < 4; ks++) {
    bf16x8 bh[8], bl[8];
#pragma unroll
    for (int nt = 0; nt < 8; nt++) {
      size_t wo = (size_t)(nt * 16 + r16) * 128 + ks * 32 + quad * 8;
      bh[nt] = *(const bf16x8*)&Whi[wo];
      bl[nt] = *(const bf16x8*)&Wlo[wo];
    }
#pragma unroll
    for (int mt = 0; mt < 2; mt++) {
      int row = wave * 32 + mt * 16 + r16;
      int pc = (ks * 4 + quad) ^ (row & 15);
      bf16x8 ah = *(const bf16x8*)&Ahi[row * 128 + pc * 8];
      bf16x8 al = *(const bf16x8*)&Alo[row * 128 + pc * 8];
#pragma unroll
      for (int nt = 0; nt < 8; nt++) {
        acc[mt][nt] = __builtin_amdgcn_mfma_f32_16x16x32_bf16(ah, bh[nt], acc[mt][nt], 0, 0, 0);
        acc[mt][nt] = __builtin_amdgcn_mfma_f32_16x16x32_bf16(al, bh[nt], acc[mt][nt], 0, 0, 0);
        acc[mt][nt] = __builtin_amdgcn_mfma_f32_16x16x32_bf16(ah, bl[nt], acc[mt][nt], 0, 0, 0);
      }
    }
  }

  // epilogue: per-lane att vector slices (channel c = nt*16 + r16, head = c>>5 = nt>>1)
  float as_l[8], ad_l[8];
#pragma unroll
  for (int nt = 0; nt < 8; nt++) {
    as_l[nt] = att_s[nt * 16 + r16];
    ad_l[nt] = att_d[nt * 16 + r16];
  }

#pragma unroll
  for (int mt = 0; mt < 2; mt++) {
#pragma unroll
    for (int reg = 0; reg < 4; reg++) {
      float ps0 = acc[mt][0][reg] * as_l[0] + acc[mt][1][reg] * as_l[1];
      float ps1 = acc[mt][2][reg] * as_l[2] + acc[mt][3][reg] * as_l[3];
      float ps2 = acc[mt][4][reg] * as_l[4] + acc[mt][5][reg] * as_l[5];
      float ps3 = acc[mt][6][reg] * as_l[6] + acc[mt][7][reg] * as_l[7];
      float pd0 = acc[mt][0][reg] * ad_l[0] + acc[mt][1][reg] * ad_l[1];
      float pd1 = acc[mt][2][reg] * ad_l[2] + acc[mt][3][reg] * ad_l[3];
      float pd2 = acc[mt][4][reg] * ad_l[4] + acc[mt][5][reg] * ad_l[5];
      float pd3 = acc[mt][6][reg] * ad_l[6] + acc[mt][7][reg] * ad_l[7];
      float am = 0.f;
#pragma unroll
      for (int nt = 0; nt < 8; nt++) am = fmaxf(am, fabsf(acc[mt][nt][reg]));
#pragma unroll
      for (int off = 1; off < 16; off <<= 1) {
        ps0 += __shfl_xor(ps0, off);
        ps1 += __shfl_xor(ps1, off);
        ps2 += __shfl_xor(ps2, off);
        ps3 += __shfl_xor(ps3, off);
        pd0 += __shfl_xor(pd0, off);
        pd1 += __shfl_xor(pd1, off);
        pd2 += __shfl_xor(pd2, off);
        pd3 += __shfl_xor(pd3, off);
        am = fmaxf(am, __shfl_xor(am, off));
      }
      int node = n0 + wave * 32 + mt * 16 + quad * 4 + reg;
      if (node < NN) {
        float amc = fmaxf(am, 1e-20f);
        float rq = 32767.f / amc;
        if (r16 == 0) {
          asrc4[node] = make_float4(ps0, ps1, ps2, ps3);
          adst4[node] = make_float4(pd0, pd1, pd2, pd3);
          scalef[node] = amc * (1.f / 32767.f);
        }
        short* dq = &hq[(size_t)node * 128 + r16];
#pragma unroll
        for (int nt = 0; nt < 8; nt++)
          dq[nt * 16] = (short)__float2int_rn(acc[mt][nt][reg] * rq);
      }
    }
  }
}

// ---------------- per-node softmax stats: 16 lanes per node, 16 nodes per block ----------------
__global__ __launch_bounds__(256) void k_stats(const float4* __restrict__ asrc,
    const float4* __restrict__ adst, const int* __restrict__ offs,
    const int* __restrict__ srcs, float4* __restrict__ mbuf, float4* __restrict__ rbuf) {
  int g = threadIdx.x >> 4, gl = threadIdx.x & 15;
  int node = blockIdx.x * 16 + g;
  if (node >= NN) return;
  int e0 = offs[node], e1 = offs[node + 1];
  float4 ad = adst[node];
  float m0 = -1e30f, m1 = -1e30f, m2 = -1e30f, m3 = -1e30f;
  float s0 = 0.f, s1 = 0.f, s2 = 0.f, s3 = 0.f;
  for (int j = e0 + gl; j < e1; j += 16) {
    float4 a = asrc[srcs[j]];
    float v, nm;
    v = a.x + ad.x; v = v > 0.f ? v : NEG * v;
    nm = fmaxf(m0, v); s0 = s0 * expf(m0 - nm) + expf(v - nm); m0 = nm;
    v = a.y + ad.y; v = v > 0.f ? v : NEG * v;
    nm = fmaxf(m1, v); s1 = s1 * expf(m1 - nm) + expf(v - nm); m1 = nm;
    v = a.z + ad.z; v = v > 0.f ? v : NEG * v;
    nm = fmaxf(m2, v); s2 = s2 * expf(m2 - nm) + expf(v - nm); m2 = nm;
    v = a.w + ad.w; v = v > 0.f ? v : NEG * v;
    nm = fmaxf(m3, v); s3 = s3 * expf(m3 - nm) + expf(v - nm); m3 = nm;
  }
#pragma unroll
  for (int off = 1; off < 16; off <<= 1) {
    float om, os, nm;
    om = __shfl_xor(m0, off); os = __shfl_xor(s0, off);
    nm = fmaxf(m0, om); s0 = s0 * expf(m0 - nm) + os * expf(om - nm); m0 = nm;
    om = __shfl_xor(m1, off); os = __shfl_xor(s1, off);
    nm = fmaxf(m1, om); s1 = s1 * expf(m1 - nm) + os * expf(om - nm); m1 = nm;
    om = __shfl_xor(m2, off); os = __shfl_xor(s2, off);
    nm = fmaxf(m2, om); s2 = s2 * expf(m2 - nm) + os * expf(om - nm); m2 = nm;
    om = __shfl_xor(m3, off); os = __shfl_xor(s3, off);
    nm = fmaxf(m3, om); s3 = s3 * expf(m3 - nm) + os * expf(om - nm); m3 = nm;
  }
  if (gl == 0) {
    mbuf[node] = make_float4(m0, m1, m2, m3);
    rbuf[node] = make_float4(1.f / (s0 + 1e-16f), 1.f / (s1 + 1e-16f),
                             1.f / (s2 + 1e-16f), 1.f / (s3 + 1e-16f));
  }
}

// ---------------- gather-aggregate (int16 rows): 4 waves/block, 1 node/wave ----------------
__global__ __launch_bounds__(256) void k_gather(const short* __restrict__ hq,
    const float* __restrict__ scalef,
    const float4* __restrict__ asrc, const float4* __restrict__ adst,
    const float4* __restrict__ mbuf, const float4* __restrict__ rbuf,
    const int* __restrict__ offs, const int* __restrict__ srcs,
    const float* __restrict__ bias, float* __restrict__ outf) {
  __shared__ int s_src[4][64];
  __shared__ float4 s_w[4][64];
  __shared__ int s_mc[4];

  int wave = threadIdx.x >> 6, lane = threadIdx.x & 63;
  int node = blockIdx.x * 4 + wave;
  int e0 = 0, e1 = 0;
  float4 ad = make_float4(0.f, 0.f, 0.f, 0.f), mm = ad, rr = ad;
  if (node < NN) {
    e0 = offs[node]; e1 = offs[node + 1];
    ad = adst[node]; mm = mbuf[node]; rr = rbuf[node];
  }
  if (lane == 0) s_mc[wave] = (e1 - e0 + 63) >> 6;
  __syncthreads();
  int maxc = max(max(s_mc[0], s_mc[1]), max(s_mc[2], s_mc[3]));

  int half = lane >> 5;
  int cl = lane & 31;
  int c0 = cl << 2;     // 4 channels per lane
  int head = cl >> 3;
  float4 acc = make_float4(0.f, 0.f, 0.f, 0.f);

  for (int c = 0; c < maxc; c++) {
    int base = e0 + (c << 6);
    __syncthreads();
    int j = base + lane;
    if (j < e1) {
      int sn = srcs[j];
      float4 a = asrc[sn];
      float sc = scalef[sn];   // fold dequant scale into the softmax weight
      float v;
      float4 w;
      v = a.x + ad.x; v = v > 0.f ? v : NEG * v; w.x = expf(v - mm.x) * rr.x * sc;
      v = a.y + ad.y; v = v > 0.f ? v : NEG * v; w.y = expf(v - mm.y) * rr.y * sc;
      v = a.z + ad.z; v = v > 0.f ? v : NEG * v; w.z = expf(v - mm.z) * rr.z * sc;
      v = a.w + ad.w; v = v > 0.f ? v : NEG * v; w.w = expf(v - mm.w) * rr.w * sc;
      s_src[wave][lane] = sn << 7;   // row offset in shorts
      s_w[wave][lane] = w;
    } else {
      s_src[wave][lane] = 0;
      s_w[wave][lane] = make_float4(0.f, 0.f, 0.f, 0.f);
    }
    __syncthreads();
    int cnt = min(64, e1 - base);
    for (int k = 0; k < cnt; k += 2) {
      int e = k + half;
      int ro = s_src[wave][e];
      float w = ((const float*)&s_w[wave][e])[head];
      s16x4 q = *(const s16x4*)&hq[ro + c0];
      acc.x = fmaf(w, (float)q[0], acc.x);
      acc.y = fmaf(w, (float)q[1], acc.y);
      acc.z = fmaf(w, (float)q[2], acc.z);
      acc.w = fmaf(w, (float)q[3], acc.w);
    }
  }

  acc.x += __shfl_xor(acc.x, 32);
  acc.y += __shfl_xor(acc.y, 32);
  acc.z += __shfl_xor(acc.z, 32);
  acc.w += __shfl_xor(acc.w, 32);

  if (half == 0 && node < NN) {
    float4 b = *(const float4*)&bias[c0];
    float o0 = acc.x + b.x, o1 = acc.y + b.y, o2 = acc.z + b.z, o3 = acc.w + b.w;
    o0 = o0 > 0.f ? o0 : expm1f(o0);
    o1 = o1 > 0.f ? o1 : expm1f(o1);
    o2 = o2 > 0.f ? o2 : expm1f(o2);
    o3 = o3 > 0.f ? o3 : expm1f(o3);
    *(float4*)&outf[(size_t)node * 128 + c0] = make_float4(o0, o1, o2, o3);
  }
}

// ---------------- mean pool ----------------
__global__ __launch_bounds__(128) void k_pool(const float* __restrict__ feat,
    const int* __restrict__ batch, float* __restrict__ pooled, float* __restrict__ cnt) {
  int n0 = blockIdx.x * 32;
  int c = threadIdx.x;
  float acc = 0.f; int curg = -1;
  for (int i = 0; i < 32; i++) {
    int n = n0 + i;
    if (n >= NN) break;
    int g = batch[n];
    if (g != curg) {
      if (curg >= 0) atomicAdd(&pooled[curg * 128 + c], acc);
      acc = 0.f; curg = g;
    }
    acc += feat[n * 128 + c];
  }
  if (curg >= 0) atomicAdd(&pooled[curg * 128 + c], acc);
  if (threadIdx.x == 0) {
    float cc = 0.f; int cg = -1;
    for (int i = 0; i < 32; i++) {
      int n = n0 + i;
      if (n >= NN) break;
      int g = batch[n];
      if (g != cg) { if (cg >= 0) atomicAdd(&cnt[cg], cc); cc = 0.f; cg = g; }
      cc += 1.f;
    }
    if (cg >= 0) atomicAdd(&cnt[cg], cc);
  }
}

// ---------------- final FC ----------------
__global__ __launch_bounds__(128) void k_fc(const float* __restrict__ pooled,
    const float* __restrict__ cnt, const float* __restrict__ fcW,
    const float* __restrict__ fcb, float* __restrict__ out) {
  int g = blockIdx.x;
  __shared__ float p[128];
  int t = threadIdx.x;
  float inv = 1.0f / fmaxf(cnt[g], 1.0f);
  p[t] = pooled[g * 128 + t] * inv;
  __syncthreads();
  if (t < OUTC) {
    float acc = fcb[t];
    const float4* wr = (const float4*)&fcW[t * 128];
    const float4* pp = (const float4*)p;
#pragma unroll
    for (int i = 0; i < 32; i++) {
      float4 w = wr[i], pv = pp[i];
      acc = fmaf(w.x, pv.x, fmaf(w.y, pv.y, fmaf(w.z, pv.z, fmaf(w.w, pv.w, acc))));
    }
    out[g * OUTC + t] = acc;
  }
}

extern "C" void kernel_launch(void* const* d_in, const int* in_sizes, int n_in,
                              void* d_out, int out_size, void* d_ws, size_t ws_size,
                              hipStream_t stream) {
  const float* x    = (const float*)d_in[0];
  const int*   ei   = (const int*)d_in[1];
  const int*   batch= (const int*)d_in[2];
  const float* W1   = (const float*)d_in[3];
  const float* as1  = (const float*)d_in[4];
  const float* ad1  = (const float*)d_in[5];
  const float* b1   = (const float*)d_in[6];
  const float* W2   = (const float*)d_in[7];
  const float* as2  = (const float*)d_in[8];
  const float* ad2  = (const float*)d_in[9];
  const float* b2   = (const float*)d_in[10];
  const float* W3   = (const float*)d_in[11];
  const float* as3  = (const float*)d_in[12];
  const float* ad3  = (const float*)d_in[13];
  const float* b3   = (const float*)d_in[14];
  const float* fcW  = (const float*)d_in[15];
  const float* fcb  = (const float*)d_in[16];
  float* out = (float*)d_out;

  char* p = (char*)d_ws;
  auto alloc = [&](size_t bytes) { char* r = p; p += (bytes + 255) & ~(size_t)255; return r; };
  short* hq     = (short*)alloc((size_t)NN * 128 * 2);
  float* scalef = (float*)alloc((size_t)NN * 4);
  float* buf0   = (float*)alloc((size_t)NN * 128 * 4);
  float* asrc   = (float*)alloc((size_t)NN * 4 * 4);
  float* adst   = (float*)alloc((size_t)NN * 4 * 4);
  float* mbuf   = (float*)alloc((size_t)NN * 4 * 4);
  float* rbuf   = (float*)alloc((size_t)NN * 4 * 4);
  int*   deg    = (int*)alloc((size_t)NN * 4);
  int*   part   = (int*)alloc((size_t)NN * 4);
  int*   bsum   = (int*)alloc(256 * 4);
  int*   offs   = (int*)alloc((size_t)(NN + 1) * 4);
  int*   cursor = (int*)alloc((size_t)NN * 4);
  int*   srcs   = (int*)alloc((size_t)EP * 4);
  float* pooled = (float*)alloc((size_t)GG * 128 * 4);
  float* cnt    = (float*)alloc((size_t)GG * 4);
  ushort* whi[3], *wlo[3];
  for (int l = 0; l < 3; l++) {
    whi[l] = (ushort*)alloc(128 * 128 * 2);
    wlo[l] = (ushort*)alloc(128 * 128 * 2);
  }

  hipMemsetAsync(deg, 0, (size_t)NN * 4, stream);
  hipMemsetAsync(cursor, 0, (size_t)NN * 4, stream);
  hipMemsetAsync(pooled, 0, (size_t)GG * 128 * 4, stream);
  hipMemsetAsync(cnt, 0, (size_t)GG * 4, stream);

  int nb = (NN + 255) / 256;
  k_hist<<<(EP + 255) / 256, 256, 0, stream>>>(ei, deg);
  k_scan1<<<nb, 256, 0, stream>>>(deg, part, bsum);
  k_scan2<<<1, 256, 0, stream>>>(bsum, nb);
  k_scan3<<<nb, 256, 0, stream>>>(part, bsum, offs);
  k_scatter<<<(EP + 255) / 256, 256, 0, stream>>>(ei, offs, cursor, srcs);

  const float* Ws[3]  = {W1, W2, W3};
  const float* ass[3] = {as1, as2, as3};
  const float* ads[3] = {ad1, ad2, ad3};
  const float* bs[3]  = {b1, b2, b3};
  for (int l = 0; l < 3; l++)
    k_split<<<64, 256, 0, stream>>>(Ws[l], whi[l], wlo[l]);

  const float* fin = x;
  for (int l = 0; l < 3; l++) {
    k_gemm_mfma<<<(NN + 127) / 128, 256, 0, stream>>>(fin, whi[l], wlo[l],
        ass[l], ads[l], hq, scalef, (float4*)asrc, (float4*)adst);
    k_stats<<<(NN + 15) / 16, 256, 0, stream>>>((const float4*)asrc, (const float4*)adst,
                                                offs, srcs, (float4*)mbuf, (float4*)rbuf);
    k_gather<<<(NN + 3) / 4, 256, 0, stream>>>(hq, scalef,
        (const float4*)asrc, (const float4*)adst,
        (const float4*)mbuf, (const float4*)rbuf,
        offs, srcs, bs[l], buf0);
    fin = buf0;
  }
  k_pool<<<(NN + 31) / 32, 128, 0, stream>>>(buf0, batch, pooled, cnt);
  k_fc<<<GG, 128, 0, stream>>>(pooled, cnt, fcW, fcb, out);
}